// Round 3
// baseline (159.421 us; speedup 1.0000x reference)
//
#include <hip/hip_runtime.h>
#include <hip/hip_bf16.h>

#define B_ 4
#define H_ 16
#define N_ 2048
#define D_ 64
#define BM 128   // q-rows per WG (32 per wave, 4 wave-pairs)
#define BN 64    // kv per iter per group

typedef __bf16 bf16;
typedef bf16 bf16x4 __attribute__((ext_vector_type(4)));
typedef bf16 bf16x8 __attribute__((ext_vector_type(8)));
typedef float f32x2 __attribute__((ext_vector_type(2)));
typedef float f32x16 __attribute__((ext_vector_type(16)));
typedef unsigned u32x2 __attribute__((ext_vector_type(2)));
typedef unsigned u32x4 __attribute__((ext_vector_type(4)));

#define SCALE_LOG2E 0.18033688011112042f  // (1/sqrt(64)) * log2(e)

#define GBL(p) ((const __attribute__((address_space(1))) void*)(p))
#define LDS(p) ((__attribute__((address_space(3))) void*)(p))

// Per (b, kv-tile T of 64): 16 KB image in per-lane FRAGMENT ORDER for 32x32x16 MFMA.
//   K half  [0,8KB):  unit p=(mt*4+ks)*64+ln : A-frag K[kv=T*64+mt*32+(ln&31)][d=ks*16+(ln>>5)*8 ..+8]
//   V half  [8,16KB): unit p=(mt*4+ks)*64+ln : A-frag V^T[d=mt*32+(ln&31)][kv=T*64+ks*16+(ln>>5)*8 ..+8]
// 4 blocks per tile (2 K-part, 2 V-part), 1 unit per thread: latency-bound gather
// gets 2x the blocks of the old layout.
__global__ __launch_bounds__(256) void convert_kv(const float* __restrict__ k,
                                                  const float* __restrict__ v,
                                                  bf16* __restrict__ img) {
    const int tile = blockIdx.x >> 2;             // b*32 + T
    const int part = blockIdx.x & 3;              // 0,1: K half  2,3: V half
    const int b = tile >> 5, T = tile & 31;
    const int pu = (part & 1) * 256 + threadIdx.x;   // 0..511 unit within half
    const int mtks = pu >> 6;
    const int ln   = pu & 63;
    const int mt = mtks >> 2, ks = mtks & 3;
    bf16* timg = img + (size_t)tile * 8192;       // 16 KB per tile

    if (part < 2) {
        // K unit
        const int kvr = T * 64 + mt * 32 + (ln & 31);
        const int d0  = ks * 16 + (ln >> 5) * 8;
        const float* src = k + ((size_t)b * N_ + kvr) * D_ + d0;
        float4 a = *(const float4*)src;
        float4 c = *(const float4*)(src + 4);
        bf16x8 o;
        o[0] = (bf16)a.x; o[1] = (bf16)a.y; o[2] = (bf16)a.z; o[3] = (bf16)a.w;
        o[4] = (bf16)c.x; o[5] = (bf16)c.y; o[6] = (bf16)c.z; o[7] = (bf16)c.w;
        *(bf16x8*)(timg + pu * 8) = o;
    } else {
        // V unit (transpose gather; lanes 0..31 contiguous in d -> coalesced 128B)
        const int d   = mt * 32 + (ln & 31);
        const int kv0 = T * 64 + ks * 16 + (ln >> 5) * 8;
        const float* src = v + ((size_t)b * N_ + kv0) * D_ + d;
        bf16x8 o;
        #pragma unroll
        for (int j = 0; j < 8; ++j) o[j] = (bf16)src[(size_t)j * D_];
        *(bf16x8*)(timg + 4096 + pu * 8) = o;
    }
}

static __device__ inline bf16x4 pack4(float a, float b, float c, float d) {
    bf16x4 r; r[0] = (bf16)a; r[1] = (bf16)b; r[2] = (bf16)c; r[3] = (bf16)d; return r;
}

// C->B half-wave exchange via v_permlane32_swap_b32. For (p,q) = swap(L,H):
//   p = {L.row0, H.row0}  == (half ? xhi : lo)
//   q = {L.row1, H.row1}  == (half ? hi  : xlo)
static __device__ inline bf16x8 cswap(bf16x4 lo, bf16x4 hi) {
    u32x2 l = __builtin_bit_cast(u32x2, lo);
    u32x2 h = __builtin_bit_cast(u32x2, hi);
    u32x2 r0 = __builtin_amdgcn_permlane32_swap(l[0], h[0], false, false);
    u32x2 r1 = __builtin_amdgcn_permlane32_swap(l[1], h[1], false, false);
    u32x4 o; o[0] = r0[0]; o[1] = r1[0]; o[2] = r0[1]; o[3] = r1[1];
    return __builtin_bit_cast(bf16x8, o);
}

// Flash attention, 32x32x16 MFMA, S^T/O^T orientation, P in registers.
// 8 waves/block: waves 0-3 (grp 0) process KV tiles 0..15, waves 4-7 (grp 1)
// tiles 16..31, for the SAME 128 q-rows; each wave owns 32 q-rows.
//
// Round-2 finding: occupancy is capped by COMBINED unified-RF allocation
// (arch VGPR + accumulator), which the CSV's VGPR_Count under-reports. The
// 64-q-row/wave variant needed ~190 combined -> hard 8 waves/CU. This variant
// halves per-wave state (acc 32, s 32, qf 16, JIT K/V frags) to fit the 128
// cliff; __launch_bounds__(512,4) enforces it -> 16 waves/CU (4/SIMD).
__global__ __launch_bounds__(512, 4) void attn_fwd(const float* __restrict__ q,
                                                   const bf16* __restrict__ img,
                                                   float* __restrict__ out) {
    __shared__ __align__(16) bf16 KV[2][2][8192];  // [group][dbuf] 16 KB tiles
    __shared__ float EXL[4][64];                   // l partials per wave-pair

    const int tid  = threadIdx.x;
    const int lane = tid & 63;
    const int wv   = tid >> 6;          // 0..7
    const int grp  = wv >> 2;           // KV half: 0 -> tiles 0..15, 1 -> 16..31
    const int wp   = wv & 3;            // wave-pair id == q-subtile
    const int half = lane >> 5;
    const int l31  = lane & 31;

    const int bh = blockIdx.y;
    const int b  = bh >> 4;
    const int q0 = blockIdx.x * BM + wp * 32;

    const bf16* tiles = img + (size_t)b * 32 * 8192;

    // Q frags (B-layout for S^T: n=q=l31, k=d=ks*16+half*8+j), pre-scaled
    bf16x8 qf[4];
    #pragma unroll
    for (int ks = 0; ks < 4; ++ks) {
        const float* src = q + ((size_t)bh * N_ + q0 + l31) * D_ + ks * 16 + half * 8;
        float4 a = *(const float4*)src;
        float4 c = *(const float4*)(src + 4);
        bf16x8 pk;
        pk[0] = (bf16)(a.x * SCALE_LOG2E); pk[1] = (bf16)(a.y * SCALE_LOG2E);
        pk[2] = (bf16)(a.z * SCALE_LOG2E); pk[3] = (bf16)(a.w * SCALE_LOG2E);
        pk[4] = (bf16)(c.x * SCALE_LOG2E); pk[5] = (bf16)(c.y * SCALE_LOG2E);
        pk[6] = (bf16)(c.z * SCALE_LOG2E); pk[7] = (bf16)(c.w * SCALE_LOG2E);
        qf[ks] = pk;
    }

    f32x16 acc[2] = {{}, {}};           // O^T tiles [mt_d] (unnormalized)
    float lacc = 0.f;

    auto issue_dma = [&](int t, int p) {
        const bf16* g = tiles + (size_t)t * 8192;
        #pragma unroll
        for (int j = 0; j < 4; ++j) {
            const int c = wp * 4 + j;             // 1 KB chunk 0..15 within group's tile
            __builtin_amdgcn_global_load_lds(GBL(g + c * 512 + lane * 8),
                                             LDS(&KV[grp][p][c * 512]), 16, 0, 0);
        }
    };

    const int t0 = grp * 16;                      // first tile of this group's range
    issue_dma(t0, 0);

    for (int it = 0; it < 16; ++it) {
        const int p = it & 1;
        __syncthreads();                          // drains tile DMA; protects buf p^1
        if (it + 1 < 16) issue_dma(t0 + it + 1, p ^ 1);

        // S^T = K Q^T : two 32x32 kv-tiles, C col=q=l31, row=kv.
        // K frags loaded just-in-time (8 live regs, not 64 preloaded).
        f32x16 s[2] = {{}, {}};
        #pragma unroll
        for (int ks = 0; ks < 4; ++ks) {
            bf16x8 k0 = *(const bf16x8*)&KV[grp][p][((0 * 4 + ks) * 64 + lane) * 8];
            bf16x8 k1 = *(const bf16x8*)&KV[grp][p][((1 * 4 + ks) * 64 + lane) * 8];
            s[0] = __builtin_amdgcn_mfma_f32_32x32x16_bf16(k0, qf[ks], s[0], 0, 0, 0);
            s[1] = __builtin_amdgcn_mfma_f32_32x32x16_bf16(k1, qf[ks], s[1], 0, 0, 0);
        }
        #pragma unroll
        for (int mt = 0; mt < 2; ++mt) {
            float pv[16];
            #pragma unroll
            for (int r = 0; r < 16; ++r) pv[r] = __builtin_amdgcn_exp2f(s[mt][r]);
            float t0s = 0.f, t1s = 0.f;
            #pragma unroll
            for (int r = 0; r < 8; ++r) { t0s += pv[r]; t1s += pv[8 + r]; }
            lacc += t0s + t1s;
            // C->B: per k-substep, half-wave permlane exchange builds P^T B-frag
            #pragma unroll
            for (int sp = 0; sp < 2; ++sp) {
                bf16x4 lo = pack4(pv[8 * sp + 0], pv[8 * sp + 1], pv[8 * sp + 2], pv[8 * sp + 3]);
                bf16x4 hi = pack4(pv[8 * sp + 4], pv[8 * sp + 5], pv[8 * sp + 6], pv[8 * sp + 7]);
                bf16x8 bfrag = cswap(lo, hi);
                const int g = mt * 2 + sp;        // kv k-step 0..3
                bf16x8 v0 = *(const bf16x8*)&KV[grp][p][4096 + ((0 * 4 + g) * 64 + lane) * 8];
                bf16x8 v1 = *(const bf16x8*)&KV[grp][p][4096 + ((1 * 4 + g) * 64 + lane) * 8];
                acc[0] = __builtin_amdgcn_mfma_f32_32x32x16_bf16(v0, bfrag, acc[0], 0, 0, 0);
                acc[1] = __builtin_amdgcn_mfma_f32_32x32x16_bf16(v1, bfrag, acc[1], 0, 0, 0);
            }
        }
    }

    // ---- combine the two KV halves (wave wp <-> wave wp+4), reusing KV LDS ----
    __syncthreads();                              // all compute reads of KV done
    float* ex = (float*)&KV[0][0][0] + wp * 2048; // 8 KB exchange region per pair

    if (grp == 1) {
        #pragma unroll
        for (int mt = 0; mt < 2; ++mt)
            #pragma unroll
            for (int rq = 0; rq < 4; ++rq) {
                const int c = mt * 4 + rq;
                float4 v4;
                v4.x = acc[mt][4 * rq + 0];
                v4.y = acc[mt][4 * rq + 1];
                v4.z = acc[mt][4 * rq + 2];
                v4.w = acc[mt][4 * rq + 3];
                *(float4*)&ex[(c * 64 + lane) * 4] = v4;   // lane-contiguous, conflict-free
            }
        EXL[wp][lane] = lacc;
    }
    __syncthreads();
    if (grp == 0) {
        lacc += EXL[wp][lane];
        #pragma unroll
        for (int mt = 0; mt < 2; ++mt)
            #pragma unroll
            for (int rq = 0; rq < 4; ++rq) {
                const int c = mt * 4 + rq;
                float4 v4 = *(const float4*)&ex[(c * 64 + lane) * 4];
                acc[mt][4 * rq + 0] += v4.x;
                acc[mt][4 * rq + 1] += v4.y;
                acc[mt][4 * rq + 2] += v4.z;
                acc[mt][4 * rq + 3] += v4.w;
            }

        // epilogue: denominator = own + partner half-wave partial; store float4
        float l = lacc + __shfl_xor(lacc, 32);
        float inv = 1.0f / l;
        const int qrow = q0 + l31;
        float* dst = out + ((size_t)bh * N_ + qrow) * D_ + 4 * half;
        #pragma unroll
        for (int mt = 0; mt < 2; ++mt)
            #pragma unroll
            for (int rq = 0; rq < 4; ++rq) {
                float4 o;
                o.x = acc[mt][4 * rq + 0] * inv;
                o.y = acc[mt][4 * rq + 1] * inv;
                o.z = acc[mt][4 * rq + 2] * inv;
                o.w = acc[mt][4 * rq + 3] * inv;
                *(float4*)(dst + mt * 32 + 8 * rq) = o;   // d = mt*32 + 8*rq + 4*half
            }
    }
}

extern "C" void kernel_launch(void* const* d_in, const int* in_sizes, int n_in,
                              void* d_out, int out_size, void* d_ws, size_t ws_size,
                              hipStream_t stream) {
    const float* q = (const float*)d_in[0];
    const float* k = (const float*)d_in[1];
    const float* v = (const float*)d_in[2];
    float* out = (float*)d_out;

    bf16* img = (bf16*)d_ws;                      // 128 tiles x 16 KB = 2 MB

    convert_kv<<<B_ * 128, 256, 0, stream>>>(k, v, img);
    dim3 grid(N_ / BM, B_ * H_);
    attn_fwd<<<grid, 512, 0, stream>>>(q, img, out);
}

// Round 4
// 158.399 us; speedup vs baseline: 1.0064x; 1.0064x over previous
//
#include <hip/hip_runtime.h>
#include <hip/hip_bf16.h>

#define B_ 4
#define H_ 16
#define N_ 2048
#define D_ 64
#define BM 128   // q-rows per WG (32 per wave, 4 wave-pairs)
#define BN 64    // kv per iter per group

typedef __bf16 bf16;
typedef bf16 bf16x4 __attribute__((ext_vector_type(4)));
typedef bf16 bf16x8 __attribute__((ext_vector_type(8)));
typedef float f32x2 __attribute__((ext_vector_type(2)));
typedef float f32x16 __attribute__((ext_vector_type(16)));
typedef unsigned u32x2 __attribute__((ext_vector_type(2)));
typedef unsigned u32x4 __attribute__((ext_vector_type(4)));

#define SCALE_LOG2E 0.18033688011112042f  // (1/sqrt(64)) * log2(e)

#define GBL(p) ((const __attribute__((address_space(1))) void*)(p))
#define LDS(p) ((__attribute__((address_space(3))) void*)(p))

// Per (b, kv-tile T of 64): 16 KB image in per-lane FRAGMENT ORDER for 32x32x16 MFMA.
//   K half  [0,8KB):  unit p=(mt*4+ks)*64+ln : A-frag K[kv=T*64+mt*32+(ln&31)][d=ks*16+(ln>>5)*8 ..+8]
//   V half  [8,16KB): unit p=(mt*4+ks)*64+ln : A-frag V^T[d=mt*32+(ln&31)][kv=T*64+ks*16+(ln>>5)*8 ..+8]
//
// Round-4: V transpose now goes through LDS. Old version did 8x 256B-stride
// global gathers per thread (latency-bound, suspected ~50+ us). New: coalesced
// float4 row reads -> LDS (padded stride 66 to spread banks) -> fragment-order
// scalar reads -> coalesced bf16x8 store. One block per tile.
__global__ __launch_bounds__(512) void convert_kv(const float* __restrict__ k,
                                                  const float* __restrict__ v,
                                                  bf16* __restrict__ img) {
    __shared__ bf16 VT[64][66];                   // stride 66 elems (132 B)
    const int tile = blockIdx.x;                  // b*32 + T
    const int b = tile >> 5, T = tile & 31;
    const int t = threadIdx.x;                    // 0..511 == unit id
    bf16* timg = img + (size_t)tile * 8192;       // 16 KB per tile

    const int mtks = t >> 6;
    const int ln   = t & 63;
    const int mt = mtks >> 2, ks = mtks & 3;

    // --- K half: direct, coalesced both sides ---
    {
        const int kvr = T * 64 + mt * 32 + (ln & 31);
        const int d0  = ks * 16 + (ln >> 5) * 8;
        const float* src = k + ((size_t)b * N_ + kvr) * D_ + d0;
        float4 a = *(const float4*)src;
        float4 c = *(const float4*)(src + 4);
        bf16x8 o;
        o[0] = (bf16)a.x; o[1] = (bf16)a.y; o[2] = (bf16)a.z; o[3] = (bf16)a.w;
        o[4] = (bf16)c.x; o[5] = (bf16)c.y; o[6] = (bf16)c.z; o[7] = (bf16)c.w;
        *(bf16x8*)(timg + t * 8) = o;
    }

    // --- V half phase 1: coalesced row load -> LDS bf16 ---
    {
        const int kv = t >> 3;                    // 0..63 (tile-local row)
        const int c8 = (t & 7) * 8;               // 0..56
        const float* src = v + ((size_t)b * N_ + T * 64 + kv) * D_ + c8;
        float4 a = *(const float4*)src;
        float4 c = *(const float4*)(src + 4);
        VT[kv][c8 + 0] = (bf16)a.x; VT[kv][c8 + 1] = (bf16)a.y;
        VT[kv][c8 + 2] = (bf16)a.z; VT[kv][c8 + 3] = (bf16)a.w;
        VT[kv][c8 + 4] = (bf16)c.x; VT[kv][c8 + 5] = (bf16)c.y;
        VT[kv][c8 + 6] = (bf16)c.z; VT[kv][c8 + 7] = (bf16)c.w;
    }
    __syncthreads();
    // --- V half phase 2: fragment-order read (<=4-way banked), coalesced store ---
    {
        const int d   = mt * 32 + (ln & 31);
        const int kv0 = ks * 16 + (ln >> 5) * 8;  // tile-local
        bf16x8 o;
        #pragma unroll
        for (int j = 0; j < 8; ++j) o[j] = VT[kv0 + j][d];
        *(bf16x8*)(timg + 4096 + t * 8) = o;
    }
}

static __device__ inline bf16x4 pack4(float a, float b, float c, float d) {
    bf16x4 r; r[0] = (bf16)a; r[1] = (bf16)b; r[2] = (bf16)c; r[3] = (bf16)d; return r;
}

// C->B half-wave exchange via v_permlane32_swap_b32. For (p,q) = swap(L,H):
//   p = {L.row0, H.row0}  == (half ? xhi : lo)
//   q = {L.row1, H.row1}  == (half ? hi  : xlo)
static __device__ inline bf16x8 cswap(bf16x4 lo, bf16x4 hi) {
    u32x2 l = __builtin_bit_cast(u32x2, lo);
    u32x2 h = __builtin_bit_cast(u32x2, hi);
    u32x2 r0 = __builtin_amdgcn_permlane32_swap(l[0], h[0], false, false);
    u32x2 r1 = __builtin_amdgcn_permlane32_swap(l[1], h[1], false, false);
    u32x4 o; o[0] = r0[0]; o[1] = r1[0]; o[2] = r0[1]; o[3] = r1[1];
    return __builtin_bit_cast(bf16x8, o);
}

// Flash attention, 32x32x16 MFMA, S^T/O^T orientation, P in registers.
// 8 waves/block: waves 0-3 (grp 0) process KV tiles 0..15, waves 4-7 (grp 1)
// tiles 16..31, for the SAME 128 q-rows; each wave owns 32 q-rows.
// 16 waves/CU resident (round-3 verified). Remaining limiter is phase
// lockstep (all waves barrier together -> pipes alternate); setprio(1)
// around MFMA clusters gives the CU scheduler arbitration when blocks
// drift out of phase (T5, m191: attn +4-7%).
__global__ __launch_bounds__(512, 4) void attn_fwd(const float* __restrict__ q,
                                                   const bf16* __restrict__ img,
                                                   float* __restrict__ out) {
    __shared__ __align__(16) bf16 KV[2][2][8192];  // [group][dbuf] 16 KB tiles
    __shared__ float EXL[4][64];                   // l partials per wave-pair

    const int tid  = threadIdx.x;
    const int lane = tid & 63;
    const int wv   = tid >> 6;          // 0..7
    const int grp  = wv >> 2;           // KV half: 0 -> tiles 0..15, 1 -> 16..31
    const int wp   = wv & 3;            // wave-pair id == q-subtile
    const int half = lane >> 5;
    const int l31  = lane & 31;

    const int bh = blockIdx.y;
    const int b  = bh >> 4;
    const int q0 = blockIdx.x * BM + wp * 32;

    const bf16* tiles = img + (size_t)b * 32 * 8192;

    // Q frags (B-layout for S^T: n=q=l31, k=d=ks*16+half*8+j), pre-scaled
    bf16x8 qf[4];
    #pragma unroll
    for (int ks = 0; ks < 4; ++ks) {
        const float* src = q + ((size_t)bh * N_ + q0 + l31) * D_ + ks * 16 + half * 8;
        float4 a = *(const float4*)src;
        float4 c = *(const float4*)(src + 4);
        bf16x8 pk;
        pk[0] = (bf16)(a.x * SCALE_LOG2E); pk[1] = (bf16)(a.y * SCALE_LOG2E);
        pk[2] = (bf16)(a.z * SCALE_LOG2E); pk[3] = (bf16)(a.w * SCALE_LOG2E);
        pk[4] = (bf16)(c.x * SCALE_LOG2E); pk[5] = (bf16)(c.y * SCALE_LOG2E);
        pk[6] = (bf16)(c.z * SCALE_LOG2E); pk[7] = (bf16)(c.w * SCALE_LOG2E);
        qf[ks] = pk;
    }

    f32x16 acc[2] = {{}, {}};           // O^T tiles [mt_d] (unnormalized)
    float lacc = 0.f;

    auto issue_dma = [&](int t, int p) {
        const bf16* g = tiles + (size_t)t * 8192;
        #pragma unroll
        for (int j = 0; j < 4; ++j) {
            const int c = wp * 4 + j;             // 1 KB chunk 0..15 within group's tile
            __builtin_amdgcn_global_load_lds(GBL(g + c * 512 + lane * 8),
                                             LDS(&KV[grp][p][c * 512]), 16, 0, 0);
        }
    };

    const int t0 = grp * 16;                      // first tile of this group's range
    issue_dma(t0, 0);

    for (int it = 0; it < 16; ++it) {
        const int p = it & 1;
        __syncthreads();                          // drains tile DMA; protects buf p^1
        if (it + 1 < 16) issue_dma(t0 + it + 1, p ^ 1);

        // S^T = K Q^T : two 32x32 kv-tiles, C col=q=l31, row=kv.
        // K frags loaded just-in-time (8 live regs, not 64 preloaded).
        f32x16 s[2] = {{}, {}};
        __builtin_amdgcn_s_setprio(1);
        #pragma unroll
        for (int ks = 0; ks < 4; ++ks) {
            bf16x8 k0 = *(const bf16x8*)&KV[grp][p][((0 * 4 + ks) * 64 + lane) * 8];
            bf16x8 k1 = *(const bf16x8*)&KV[grp][p][((1 * 4 + ks) * 64 + lane) * 8];
            s[0] = __builtin_amdgcn_mfma_f32_32x32x16_bf16(k0, qf[ks], s[0], 0, 0, 0);
            s[1] = __builtin_amdgcn_mfma_f32_32x32x16_bf16(k1, qf[ks], s[1], 0, 0, 0);
        }
        __builtin_amdgcn_s_setprio(0);
        #pragma unroll
        for (int mt = 0; mt < 2; ++mt) {
            float pv[16];
            #pragma unroll
            for (int r = 0; r < 16; ++r) pv[r] = __builtin_amdgcn_exp2f(s[mt][r]);
            float t0s = 0.f, t1s = 0.f;
            #pragma unroll
            for (int r = 0; r < 8; ++r) { t0s += pv[r]; t1s += pv[8 + r]; }
            lacc += t0s + t1s;
            // C->B: per k-substep, half-wave permlane exchange builds P^T B-frag
            #pragma unroll
            for (int sp = 0; sp < 2; ++sp) {
                bf16x4 lo = pack4(pv[8 * sp + 0], pv[8 * sp + 1], pv[8 * sp + 2], pv[8 * sp + 3]);
                bf16x4 hi = pack4(pv[8 * sp + 4], pv[8 * sp + 5], pv[8 * sp + 6], pv[8 * sp + 7]);
                bf16x8 bfrag = cswap(lo, hi);
                const int g = mt * 2 + sp;        // kv k-step 0..3
                bf16x8 v0 = *(const bf16x8*)&KV[grp][p][4096 + ((0 * 4 + g) * 64 + lane) * 8];
                bf16x8 v1 = *(const bf16x8*)&KV[grp][p][4096 + ((1 * 4 + g) * 64 + lane) * 8];
                __builtin_amdgcn_s_setprio(1);
                acc[0] = __builtin_amdgcn_mfma_f32_32x32x16_bf16(v0, bfrag, acc[0], 0, 0, 0);
                acc[1] = __builtin_amdgcn_mfma_f32_32x32x16_bf16(v1, bfrag, acc[1], 0, 0, 0);
                __builtin_amdgcn_s_setprio(0);
            }
        }
    }

    // ---- combine the two KV halves (wave wp <-> wave wp+4), reusing KV LDS ----
    __syncthreads();                              // all compute reads of KV done
    float* ex = (float*)&KV[0][0][0] + wp * 2048; // 8 KB exchange region per pair

    if (grp == 1) {
        #pragma unroll
        for (int mt = 0; mt < 2; ++mt)
            #pragma unroll
            for (int rq = 0; rq < 4; ++rq) {
                const int c = mt * 4 + rq;
                float4 v4;
                v4.x = acc[mt][4 * rq + 0];
                v4.y = acc[mt][4 * rq + 1];
                v4.z = acc[mt][4 * rq + 2];
                v4.w = acc[mt][4 * rq + 3];
                *(float4*)&ex[(c * 64 + lane) * 4] = v4;   // lane-contiguous, conflict-free
            }
        EXL[wp][lane] = lacc;
    }
    __syncthreads();
    if (grp == 0) {
        lacc += EXL[wp][lane];
        #pragma unroll
        for (int mt = 0; mt < 2; ++mt)
            #pragma unroll
            for (int rq = 0; rq < 4; ++rq) {
                const int c = mt * 4 + rq;
                float4 v4 = *(const float4*)&ex[(c * 64 + lane) * 4];
                acc[mt][4 * rq + 0] += v4.x;
                acc[mt][4 * rq + 1] += v4.y;
                acc[mt][4 * rq + 2] += v4.z;
                acc[mt][4 * rq + 3] += v4.w;
            }

        // epilogue: denominator = own + partner half-wave partial; store float4
        float l = lacc + __shfl_xor(lacc, 32);
        float inv = 1.0f / l;
        const int qrow = q0 + l31;
        float* dst = out + ((size_t)bh * N_ + qrow) * D_ + 4 * half;
        #pragma unroll
        for (int mt = 0; mt < 2; ++mt)
            #pragma unroll
            for (int rq = 0; rq < 4; ++rq) {
                float4 o;
                o.x = acc[mt][4 * rq + 0] * inv;
                o.y = acc[mt][4 * rq + 1] * inv;
                o.z = acc[mt][4 * rq + 2] * inv;
                o.w = acc[mt][4 * rq + 3] * inv;
                *(float4*)(dst + mt * 32 + 8 * rq) = o;   // d = mt*32 + 8*rq + 4*half
            }
    }
}

extern "C" void kernel_launch(void* const* d_in, const int* in_sizes, int n_in,
                              void* d_out, int out_size, void* d_ws, size_t ws_size,
                              hipStream_t stream) {
    const float* q = (const float*)d_in[0];
    const float* k = (const float*)d_in[1];
    const float* v = (const float*)d_in[2];
    float* out = (float*)d_out;

    bf16* img = (bf16*)d_ws;                      // 128 tiles x 16 KB = 2 MB

    convert_kv<<<B_ * 32, 512, 0, stream>>>(k, v, img);
    dim3 grid(N_ / BM, B_ * H_);
    attn_fwd<<<grid, 512, 0, stream>>>(q, img, out);
}